// Round 7
// baseline (5507.133 us; speedup 1.0000x reference)
//
#include <hip/hip_runtime.h>
#include <stdint.h>

#define BB 8
#define NN 2048
#define DD 64
#define REGv 0.1f
#define NUM_ITERS 50
#define EPS_NORM 1e-8f
#define EPS_SINK 1e-10f
#define GRID_P 256u
#define NBAR 128

typedef float f4 __attribute__((ext_vector_type(4)));
#define KEEP(x) asm volatile("" : "+v"(x))

__device__ __forceinline__ float dotf4(f4 a, f4 b) {
    return a.x * b.x + a.y * b.y + a.z * b.z + a.w * b.w;
}

// ---------------- init: maxd2 = 0, barrier counters = 0 ----------------
__global__ void init_k(unsigned* maxd, unsigned* bar) {
    int t = threadIdx.x;
    if (t < BB) maxd[t] = 0u;
    if (t < NBAR) bar[t] = 0u;
}

// ---------------- row squared norms (one wave per row) ----------------
__global__ void sq_k(const float* __restrict__ x0, const float* __restrict__ x1,
                     float* __restrict__ sq0, float* __restrict__ sq1) {
    int w = (blockIdx.x * 256 + threadIdx.x) >> 6;
    int lane = threadIdx.x & 63;
    if (w >= 2 * BB * NN) return;
    const float* src = (w < BB * NN) ? x0 : x1;
    int r = (w < BB * NN) ? w : w - BB * NN;
    float val = src[(size_t)r * DD + lane];
    float s = val * val;
    #pragma unroll
    for (int off = 32; off; off >>= 1) s += __shfl_xor(s, off);
    if (lane == 0) ((w < BB * NN) ? sq0 : sq1)[r] = s;
}

// ---------------- fused cdist: WRITE=0 -> max(d2); WRITE=1 -> K=exp ----------------
template<int WRITE>
__global__ __launch_bounds__(256) void distc_k(const float* __restrict__ x0,
                                               const float* __restrict__ x1,
                                               const float* __restrict__ sq0,
                                               const float* __restrict__ sq1,
                                               float* __restrict__ Kd,
                                               unsigned* __restrict__ maxd) {
    __shared__ float x0s[128 * 68];
    __shared__ float x1t[64 * 68];
    __shared__ float wred[4];
    int bid = blockIdx.x;
    int b = bid >> 9;
    int tile = bid & 511;
    int ti = tile >> 5, tj = tile & 31;
    int i0 = ti * 128, j0 = tj * 64;
    int t = threadIdx.x;

    const float4* g0 = (const float4*)(x0 + ((size_t)b * NN + i0) * DD);
    #pragma unroll
    for (int rep = 0; rep < 8; rep++) {
        int e = rep * 256 + t;
        int row = e >> 4, c4 = e & 15;
        *(float4*)&x0s[row * 68 + c4 * 4] = g0[row * 16 + c4];
    }
    const float4* g1 = (const float4*)(x1 + ((size_t)b * NN + j0) * DD);
    #pragma unroll
    for (int rep = 0; rep < 4; rep++) {
        int e = rep * 256 + t;
        int row = e >> 4, c4 = e & 15;
        float4 a = g1[row * 16 + c4];
        x1t[(c4 * 4 + 0) * 68 + row] = a.x;
        x1t[(c4 * 4 + 1) * 68 + row] = a.y;
        x1t[(c4 * 4 + 2) * 68 + row] = a.z;
        x1t[(c4 * 4 + 3) * 68 + row] = a.w;
    }
    __syncthreads();

    int tx = t & 15, ty = t >> 4;
    float4 acc4[8];
    #pragma unroll
    for (int di = 0; di < 8; di++) acc4[di] = make_float4(0.f, 0.f, 0.f, 0.f);

    #pragma unroll
    for (int k4 = 0; k4 < 16; k4++) {
        float4 b0 = *(const float4*)&x1t[(k4 * 4 + 0) * 68 + tx * 4];
        float4 b1 = *(const float4*)&x1t[(k4 * 4 + 1) * 68 + tx * 4];
        float4 b2 = *(const float4*)&x1t[(k4 * 4 + 2) * 68 + tx * 4];
        float4 b3 = *(const float4*)&x1t[(k4 * 4 + 3) * 68 + tx * 4];
        #pragma unroll
        for (int di = 0; di < 8; di++) {
            float4 a = *(const float4*)&x0s[(ty * 8 + di) * 68 + k4 * 4];
            acc4[di].x += a.x * b0.x + a.y * b1.x + a.z * b2.x + a.w * b3.x;
            acc4[di].y += a.x * b0.y + a.y * b1.y + a.z * b2.y + a.w * b3.y;
            acc4[di].z += a.x * b0.z + a.y * b1.z + a.z * b2.z + a.w * b3.z;
            acc4[di].w += a.x * b0.w + a.y * b1.w + a.z * b2.w + a.w * b3.w;
        }
    }

    int ib = b * NN + i0 + ty * 8;
    float4 s1 = *(const float4*)&sq1[b * NN + j0 + tx * 4];

    if (WRITE) {
        float mv = sqrtf(__uint_as_float(maxd[b])) + EPS_NORM;
        #pragma unroll
        for (int di = 0; di < 8; di++) {
            float s0 = sq0[ib + di];
            float4 o;
            o.x = expf(-((sqrtf(fmaxf(s0 + s1.x - 2.f * acc4[di].x, 0.f)) / mv) / REGv));
            o.y = expf(-((sqrtf(fmaxf(s0 + s1.y - 2.f * acc4[di].y, 0.f)) / mv) / REGv));
            o.z = expf(-((sqrtf(fmaxf(s0 + s1.z - 2.f * acc4[di].z, 0.f)) / mv) / REGv));
            o.w = expf(-((sqrtf(fmaxf(s0 + s1.w - 2.f * acc4[di].w, 0.f)) / mv) / REGv));
            *(float4*)&Kd[(size_t)(ib + di) * NN + j0 + tx * 4] = o;
        }
    } else {
        float lm = 0.0f;
        #pragma unroll
        for (int di = 0; di < 8; di++) {
            float s0 = sq0[ib + di];
            lm = fmaxf(lm, fmaxf(s0 + s1.x - 2.f * acc4[di].x, 0.f));
            lm = fmaxf(lm, fmaxf(s0 + s1.y - 2.f * acc4[di].y, 0.f));
            lm = fmaxf(lm, fmaxf(s0 + s1.z - 2.f * acc4[di].z, 0.f));
            lm = fmaxf(lm, fmaxf(s0 + s1.w - 2.f * acc4[di].w, 0.f));
        }
        #pragma unroll
        for (int off = 32; off; off >>= 1) lm = fmaxf(lm, __shfl_xor(lm, off));
        if ((t & 63) == 0) wred[t >> 6] = lm;
        __syncthreads();
        if (t == 0) {
            float m = fmaxf(fmaxf(wred[0], wred[1]), fmaxf(wred[2], wred[3]));
            atomicMax(&maxd[b], __float_as_uint(m));  // d2 >= 0: uint cmp == float cmp
        }
    }
}

// ---------------- hand-rolled grid barrier (256 co-resident blocks) ----------------
__device__ __forceinline__ void gbar(unsigned* c, int t) {
    __syncthreads();   // drain block stores before arrive
    if (t == 0) {
        __threadfence();                 // release (agent scope)
        atomicAdd(c, 1u);
        while (__hip_atomic_load(c, __ATOMIC_RELAXED, __HIP_MEMORY_SCOPE_AGENT) < GRID_P)
            __builtin_amdgcn_s_sleep(1);
        __threadfence();                 // acquire
    }
    __syncthreads();
}

// ---------------- persistent Sinkhorn: single K-visit per iteration ----------------
// 256 blocks x 512 threads (8 waves), 1 block/CU. Block q: batch b=q>>5, rows g*64..+63.
// Wave w: 2 LDS-resident rows {2w,2w+1}; 6 streamed rows {16+p*16+2w, +1}, p=0..2,
// each carried in 16 f4 regs between its u-dot and sigma-contribution (single read).
// Latin rotation: reg/sigma slot k <-> physical f4-col chunk (w+k)&7, col idx
// ((w+k)&7)*64 + l  => all per-lane register indices STATIC; 8-wave sigma merge
// runs in 8 conflict-free steps.
__global__ __launch_bounds__(512)
void persist_k(const float* __restrict__ Kd,
               float* __restrict__ partial,
               float* __restrict__ vglob,
               unsigned* __restrict__ bar,
               int* __restrict__ out) {
    __shared__ f4 Kl4[16 * 512];   // 128 KB: 16 LDS-resident K rows
    __shared__ f4 vbuf4[512];      // 8 KB: v for this batch
    __shared__ f4 sgbuf[512];      // 8 KB: sigma merge / vred scratch
    __shared__ float ubuf[64];     // final-iter u per local row

    const int t = threadIdx.x;
    const int l = t & 63;
    const int w = t >> 6;          // 0..7
    const int q = blockIdx.x;
    const int b = q >> 5;
    const int g = q & 31;
    const size_t rowbase = (size_t)(b * NN + g * 64);
    const f4* Kg = (const f4*)Kd;

    // stage LDS-resident rows (local rows 2w, 2w+1), rotated layout
    #pragma unroll
    for (int rr = 0; rr < 2; rr++) {
        int lr = 2 * w + rr;
        #pragma unroll
        for (int k = 0; k < 8; k++) {
            int idx = (((w + k) & 7) << 6) + l;
            Kl4[lr * 512 + idx] = Kg[(rowbase + lr) * 512 + idx];
        }
    }
    vbuf4[t] = (f4){1.0f / NN, 1.0f / NN, 1.0f / NN, 1.0f / NN};

    for (int it = 0; it < NUM_ITERS; ++it) {
        sgbuf[t] = (f4){0.f, 0.f, 0.f, 0.f};
        __syncthreads();   // vbuf + zeroed sgbuf visible

        f4 sg[8];
        #pragma unroll
        for (int k = 0; k < 8; k++) sg[k] = (f4){0.f, 0.f, 0.f, 0.f};

        // ---- LDS-resident rows: dot -> u -> sigma contrib ----
        #pragma unroll
        for (int rr = 0; rr < 2; rr++) {
            int lr = 2 * w + rr;
            float dp = 0.f;
            #pragma unroll
            for (int k = 0; k < 8; k++) {
                int idx = (((w + k) & 7) << 6) + l;
                dp += dotf4(Kl4[lr * 512 + idx], vbuf4[idx]);
            }
            #pragma unroll
            for (int off = 32; off; off >>= 1) dp += __shfl_xor(dp, off);
            float uu = 1.0f / (dp + EPS_SINK);
            if (l == 0) ubuf[lr] = uu;
            #pragma unroll
            for (int k = 0; k < 8; k++) {
                int idx = (((w + k) & 7) << 6) + l;
                sg[k] += uu * Kl4[lr * 512 + idx];
            }
        }

        // ---- streamed rows: 3 passes x 2 rows, single global read per row ----
        #pragma unroll
        for (int p = 0; p < 3; p++) {
            int lr0 = 16 + p * 16 + 2 * w;
            f4 c0[8], c1[8];
            #pragma unroll
            for (int k = 0; k < 8; k++) {
                int idx = (((w + k) & 7) << 6) + l;
                c0[k] = Kg[(rowbase + lr0) * 512 + idx];
                c1[k] = Kg[(rowbase + lr0 + 1) * 512 + idx];
                KEEP(c0[k]); KEEP(c1[k]);
            }
            float dp0 = 0.f, dp1 = 0.f;
            #pragma unroll
            for (int k = 0; k < 8; k++) {
                int idx = (((w + k) & 7) << 6) + l;
                f4 vk = vbuf4[idx];
                dp0 += dotf4(c0[k], vk);
                dp1 += dotf4(c1[k], vk);
            }
            #pragma unroll
            for (int off = 32; off; off >>= 1) {
                dp0 += __shfl_xor(dp0, off);
                dp1 += __shfl_xor(dp1, off);
            }
            float u0 = 1.0f / (dp0 + EPS_SINK);
            float u1 = 1.0f / (dp1 + EPS_SINK);
            if (l == 0) { ubuf[lr0] = u0; ubuf[lr0 + 1] = u1; }
            #pragma unroll
            for (int k = 0; k < 8; k++) sg[k] += u0 * c0[k] + u1 * c1[k];
        }

        // ---- sigma merge: 8 latin-square steps, waves hit disjoint chunks ----
        #pragma unroll
        for (int s = 0; s < 8; s++) {
            int idx = (((w + s) & 7) << 6) + l;
            sgbuf[idx] = sgbuf[idx] + sg[s];
            __syncthreads();
        }

        // ---- write block partial (8 KB) ----
        ((f4*)partial)[(size_t)q * 512 + t] = sgbuf[t];
        gbar(&bar[2 * it], t);

        // ---- distributed v-reduce: block q -> 16 f4 of vglob ----
        {
            int c4 = g * 16 + (t & 15);
            int prow = t >> 4;     // 0..31
            f4 pv = ((const f4*)partial)[(size_t)(b * 32 + prow) * 512 + c4];
            #pragma unroll
            for (int off = 16; off <= 32; off <<= 1) {
                pv.x += __shfl_xor(pv.x, off);
                pv.y += __shfl_xor(pv.y, off);
                pv.z += __shfl_xor(pv.z, off);
                pv.w += __shfl_xor(pv.w, off);
            }
            if (l < 16) sgbuf[w * 16 + l] = pv;
            __syncthreads();
            if (t < 16) {
                f4 s = sgbuf[t];
                #pragma unroll
                for (int ww = 1; ww < 8; ww++) s += sgbuf[ww * 16 + t];
                f4 vv;
                vv.x = 1.0f / (s.x + EPS_SINK);
                vv.y = 1.0f / (s.y + EPS_SINK);
                vv.z = 1.0f / (s.z + EPS_SINK);
                vv.w = 1.0f / (s.w + EPS_SINK);
                ((f4*)vglob)[q * 16 + t] = vv;
            }
        }
        gbar(&bar[2 * it + 1], t);

        // ---- reload v for this batch ----
        vbuf4[t] = ((const f4*)vglob)[b * 512 + t];
    }
    __syncthreads();

    // ---- argmax of P = (u*K)*v per row (explicit index tie-break, rotated scan) ----
    // LDS-resident rows
    #pragma unroll
    for (int rr = 0; rr < 2; rr++) {
        int lr = 2 * w + rr;
        float uu = ubuf[lr];
        float best = -1.0f;
        int bi = 0x7fffffff;
        #pragma unroll
        for (int k = 0; k < 8; k++) {
            int idx = (((w + k) & 7) << 6) + l;
            f4 vk = vbuf4[idx];
            f4 kr = Kl4[lr * 512 + idx];
            f4 pp;
            pp.x = (uu * kr.x) * vk.x;
            pp.y = (uu * kr.y) * vk.y;
            pp.z = (uu * kr.z) * vk.z;
            pp.w = (uu * kr.w) * vk.w;
            int j0 = idx * 4;
            if (pp.x > best || (pp.x == best && j0     < bi)) { best = pp.x; bi = j0;     }
            if (pp.y > best || (pp.y == best && j0 + 1 < bi)) { best = pp.y; bi = j0 + 1; }
            if (pp.z > best || (pp.z == best && j0 + 2 < bi)) { best = pp.z; bi = j0 + 2; }
            if (pp.w > best || (pp.w == best && j0 + 3 < bi)) { best = pp.w; bi = j0 + 3; }
        }
        #pragma unroll
        for (int off = 32; off; off >>= 1) {
            float ov = __shfl_xor(best, off);
            int oi = __shfl_xor(bi, off);
            if (ov > best || (ov == best && oi < bi)) { best = ov; bi = oi; }
        }
        if (l == 0) out[(size_t)(rowbase + lr)] = bi;
    }
    // streamed rows (re-read once)
    #pragma unroll
    for (int p = 0; p < 3; p++) {
        #pragma unroll
        for (int rr = 0; rr < 2; rr++) {
            int lr = 16 + p * 16 + 2 * w + rr;
            float uu = ubuf[lr];
            float best = -1.0f;
            int bi = 0x7fffffff;
            #pragma unroll
            for (int k = 0; k < 8; k++) {
                int idx = (((w + k) & 7) << 6) + l;
                f4 vk = vbuf4[idx];
                f4 kr = Kg[(rowbase + lr) * 512 + idx];
                f4 pp;
                pp.x = (uu * kr.x) * vk.x;
                pp.y = (uu * kr.y) * vk.y;
                pp.z = (uu * kr.z) * vk.z;
                pp.w = (uu * kr.w) * vk.w;
                int j0 = idx * 4;
                if (pp.x > best || (pp.x == best && j0     < bi)) { best = pp.x; bi = j0;     }
                if (pp.y > best || (pp.y == best && j0 + 1 < bi)) { best = pp.y; bi = j0 + 1; }
                if (pp.z > best || (pp.z == best && j0 + 2 < bi)) { best = pp.z; bi = j0 + 2; }
                if (pp.w > best || (pp.w == best && j0 + 3 < bi)) { best = pp.w; bi = j0 + 3; }
            }
            #pragma unroll
            for (int off = 32; off; off >>= 1) {
                float ov = __shfl_xor(best, off);
                int oi = __shfl_xor(bi, off);
                if (ov > best || (ov == best && oi < bi)) { best = ov; bi = oi; }
            }
            if (l == 0) out[(size_t)(rowbase + lr)] = bi;
        }
    }
}

extern "C" void kernel_launch(void* const* d_in, const int* in_sizes, int n_in,
                              void* d_out, int out_size, void* d_ws, size_t ws_size,
                              hipStream_t stream) {
    const float* x0 = (const float*)d_in[0];
    const float* x1 = (const float*)d_in[1];
    int* out = (int*)d_out;
    char* ws = (char*)d_ws;

    // ws layout (bytes)
    float* Kd      = (float*)(ws + 0ull);                 // 134217728
    float* partial = (float*)(ws + 134217728ull);         // 2097152
    float* vglob   = (float*)(ws + 136314880ull);         // 65536
    float* sq0     = (float*)(ws + 136380416ull);         // 65536
    float* sq1     = (float*)(ws + 136445952ull);         // 65536
    unsigned* maxd = (unsigned*)(ws + 136511488ull);      // 32
    unsigned* bar  = (unsigned*)(ws + 136511520ull);      // 512

    init_k<<<1, 256, 0, stream>>>(maxd, bar);
    sq_k<<<8192, 256, 0, stream>>>(x0, x1, sq0, sq1);
    distc_k<0><<<4096, 256, 0, stream>>>(x0, x1, sq0, sq1, Kd, maxd);
    distc_k<1><<<4096, 256, 0, stream>>>(x0, x1, sq0, sq1, Kd, maxd);
    persist_k<<<256, 512, 0, stream>>>(Kd, partial, vglob, bar, out);
}

// Round 8
// 4216.982 us; speedup vs baseline: 1.3059x; 1.3059x over previous
//
#include <hip/hip_runtime.h>
#include <stdint.h>

#define BB 8
#define NN 2048
#define DD 64
#define REGv 0.1f
#define NUM_ITERS 50
#define EPS_NORM 1e-8f
#define EPS_SINK 1e-10f
#define GRID_P 256u
#define NBAR 128

typedef float f4 __attribute__((ext_vector_type(4)));

__device__ __forceinline__ float dotf4(f4 a, f4 b) {
    return a.x * b.x + a.y * b.y + a.z * b.z + a.w * b.w;
}

// ---------------- init: maxd2 = 0, barrier counters = 0 ----------------
__global__ void init_k(unsigned* maxd, unsigned* bar) {
    int t = threadIdx.x;
    if (t < BB) maxd[t] = 0u;
    if (t < NBAR) bar[t] = 0u;
}

// ---------------- row squared norms (one wave per row) ----------------
__global__ void sq_k(const float* __restrict__ x0, const float* __restrict__ x1,
                     float* __restrict__ sq0, float* __restrict__ sq1) {
    int w = (blockIdx.x * 256 + threadIdx.x) >> 6;
    int lane = threadIdx.x & 63;
    if (w >= 2 * BB * NN) return;
    const float* src = (w < BB * NN) ? x0 : x1;
    int r = (w < BB * NN) ? w : w - BB * NN;
    float val = src[(size_t)r * DD + lane];
    float s = val * val;
    #pragma unroll
    for (int off = 32; off; off >>= 1) s += __shfl_xor(s, off);
    if (lane == 0) ((w < BB * NN) ? sq0 : sq1)[r] = s;
}

// ---------------- fused cdist: WRITE=0 -> max(d2); WRITE=1 -> K=exp ----------------
// x0s: stride 64, XOR-swizzled columns (phys_c4 = c4 ^ ((row>>3)&3)) -> a-reads conflict-free
template<int WRITE>
__global__ __launch_bounds__(256) void distc_k(const float* __restrict__ x0,
                                               const float* __restrict__ x1,
                                               const float* __restrict__ sq0,
                                               const float* __restrict__ sq1,
                                               float* __restrict__ Kd,
                                               unsigned* __restrict__ maxd) {
    __shared__ float x0s[128 * 64];
    __shared__ float x1t[64 * 68];
    __shared__ float wred[4];
    int bid = blockIdx.x;
    int b = bid >> 9;
    int tile = bid & 511;
    int ti = tile >> 5, tj = tile & 31;
    int i0 = ti * 128, j0 = tj * 64;
    int t = threadIdx.x;

    const float4* g0 = (const float4*)(x0 + ((size_t)b * NN + i0) * DD);
    #pragma unroll
    for (int rep = 0; rep < 8; rep++) {
        int e = rep * 256 + t;
        int row = e >> 4, c4 = e & 15;
        int pc = c4 ^ ((row >> 3) & 3);     // XOR swizzle
        *(float4*)&x0s[row * 64 + pc * 4] = g0[row * 16 + c4];
    }
    const float4* g1 = (const float4*)(x1 + ((size_t)b * NN + j0) * DD);
    #pragma unroll
    for (int rep = 0; rep < 4; rep++) {
        int e = rep * 256 + t;
        int row = e >> 4, c4 = e & 15;
        float4 a = g1[row * 16 + c4];
        x1t[(c4 * 4 + 0) * 68 + row] = a.x;
        x1t[(c4 * 4 + 1) * 68 + row] = a.y;
        x1t[(c4 * 4 + 2) * 68 + row] = a.z;
        x1t[(c4 * 4 + 3) * 68 + row] = a.w;
    }
    __syncthreads();

    int tx = t & 15, ty = t >> 4;
    float4 acc4[8];
    #pragma unroll
    for (int di = 0; di < 8; di++) acc4[di] = make_float4(0.f, 0.f, 0.f, 0.f);

    #pragma unroll
    for (int k4 = 0; k4 < 16; k4++) {
        float4 b0 = *(const float4*)&x1t[(k4 * 4 + 0) * 68 + tx * 4];
        float4 b1 = *(const float4*)&x1t[(k4 * 4 + 1) * 68 + tx * 4];
        float4 b2 = *(const float4*)&x1t[(k4 * 4 + 2) * 68 + tx * 4];
        float4 b3 = *(const float4*)&x1t[(k4 * 4 + 3) * 68 + tx * 4];
        int pk = (k4 ^ (ty & 3)) << 2;      // physical col of logical k4 for rows ty*8+di
        #pragma unroll
        for (int di = 0; di < 8; di++) {
            float4 a = *(const float4*)&x0s[(ty * 8 + di) * 64 + pk];
            acc4[di].x += a.x * b0.x + a.y * b1.x + a.z * b2.x + a.w * b3.x;
            acc4[di].y += a.x * b0.y + a.y * b1.y + a.z * b2.y + a.w * b3.y;
            acc4[di].z += a.x * b0.z + a.y * b1.z + a.z * b2.z + a.w * b3.z;
            acc4[di].w += a.x * b0.w + a.y * b1.w + a.z * b2.w + a.w * b3.w;
        }
    }

    int ib = b * NN + i0 + ty * 8;
    float4 s1 = *(const float4*)&sq1[b * NN + j0 + tx * 4];

    if (WRITE) {
        float mv = sqrtf(__uint_as_float(maxd[b])) + EPS_NORM;
        #pragma unroll
        for (int di = 0; di < 8; di++) {
            float s0 = sq0[ib + di];
            float4 o;
            o.x = expf(-((sqrtf(fmaxf(s0 + s1.x - 2.f * acc4[di].x, 0.f)) / mv) / REGv));
            o.y = expf(-((sqrtf(fmaxf(s0 + s1.y - 2.f * acc4[di].y, 0.f)) / mv) / REGv));
            o.z = expf(-((sqrtf(fmaxf(s0 + s1.z - 2.f * acc4[di].z, 0.f)) / mv) / REGv));
            o.w = expf(-((sqrtf(fmaxf(s0 + s1.w - 2.f * acc4[di].w, 0.f)) / mv) / REGv));
            *(float4*)&Kd[(size_t)(ib + di) * NN + j0 + tx * 4] = o;
        }
    } else {
        float lm = 0.0f;
        #pragma unroll
        for (int di = 0; di < 8; di++) {
            float s0 = sq0[ib + di];
            lm = fmaxf(lm, fmaxf(s0 + s1.x - 2.f * acc4[di].x, 0.f));
            lm = fmaxf(lm, fmaxf(s0 + s1.y - 2.f * acc4[di].y, 0.f));
            lm = fmaxf(lm, fmaxf(s0 + s1.z - 2.f * acc4[di].z, 0.f));
            lm = fmaxf(lm, fmaxf(s0 + s1.w - 2.f * acc4[di].w, 0.f));
        }
        #pragma unroll
        for (int off = 32; off; off >>= 1) lm = fmaxf(lm, __shfl_xor(lm, off));
        if ((t & 63) == 0) wred[t >> 6] = lm;
        __syncthreads();
        if (t == 0) {
            float m = fmaxf(fmaxf(wred[0], wred[1]), fmaxf(wred[2], wred[3]));
            atomicMax(&maxd[b], __float_as_uint(m));  // d2 >= 0: uint cmp == float cmp
        }
    }
}

// ---------------- hand-rolled grid barrier (256 co-resident blocks) ----------------
__device__ __forceinline__ void gbar(unsigned* c, int t) {
    __syncthreads();   // drains vmcnt per thread before barrier -> stores complete
    if (t == 0) {
        __threadfence();                 // release (agent scope)
        atomicAdd(c, 1u);
        while (__hip_atomic_load(c, __ATOMIC_RELAXED, __HIP_MEMORY_SCOPE_AGENT) < GRID_P)
            __builtin_amdgcn_s_sleep(1);
        __threadfence();                 // acquire (invalidates CU L1)
    }
    __syncthreads();
}

// ---------------- persistent Sinkhorn: R2 register profile, 16 rows LDS-resident ----------------
// 256 blocks x 512 threads, 1 block/CU (130 KB LDS). Block q: batch b=q>>5, rows g*64..+63.
// Thread t owns f4-column t (4 cols). Per iter: 4 sub-chunks of 16 rows; sc0 from LDS,
// sc1-3 streamed from global ONCE (kk[16] = 64 VGPR carry, sigma acc = 1 f4).
__global__ __launch_bounds__(512)
void persist_k(const float* __restrict__ Kd,
               float* __restrict__ partial,
               float* __restrict__ vglob,
               float* __restrict__ uglob,
               unsigned* __restrict__ bar) {
    __shared__ f4 Kl4[16 * 512];   // 128 KB: rows 0..15 resident
    __shared__ float red[8][16];
    __shared__ float uu_s[16];
    __shared__ f4 sgbuf[128];      // vred scratch

    const int t = threadIdx.x;
    const int l = t & 63;
    const int w = t >> 6;
    const int q = blockIdx.x;
    const int b = q >> 5;
    const int g = q & 31;
    const size_t rowbase = (size_t)(b * NN + g * 64);
    const f4* Kg = (const f4*)Kd;

    // stage rows 0..15 into LDS (read once, never again)
    #pragma unroll
    for (int r = 0; r < 16; r++)
        Kl4[r * 512 + t] = Kg[(rowbase + r) * 512 + t];

    f4 vk = (f4){1.0f / NN, 1.0f / NN, 1.0f / NN, 1.0f / NN};
    __syncthreads();

    for (int it = 0; it < NUM_ITERS; ++it) {
        f4 acc = (f4){0.f, 0.f, 0.f, 0.f};

        #pragma unroll
        for (int sc = 0; sc < 4; ++sc) {
            f4 kk[16];
            if (sc == 0) {
                #pragma unroll
                for (int r = 0; r < 16; r++) kk[r] = Kl4[r * 512 + t];
            } else {
                const f4* src = Kg + (rowbase + sc * 16) * 512;
                #pragma unroll
                for (int r = 0; r < 16; r++) kk[r] = src[(size_t)r * 512 + t];
            }

            // row dots -> u (R2-proven reduction)
            float dp[16];
            #pragma unroll
            for (int r = 0; r < 16; r++) dp[r] = dotf4(kk[r], vk);
            #pragma unroll
            for (int r = 0; r < 16; r++)
                #pragma unroll
                for (int off = 32; off; off >>= 1) dp[r] += __shfl_xor(dp[r], off);
            if (l == 0) {
                #pragma unroll
                for (int r = 0; r < 16; r++) red[w][r] = dp[r];
            }
            __syncthreads();
            if (t < 16) {
                float s = red[0][t] + red[1][t] + red[2][t] + red[3][t] +
                          red[4][t] + red[5][t] + red[6][t] + red[7][t];
                float uu = 1.0f / (s + EPS_SINK);
                uu_s[t] = uu;
                uglob[rowbase + sc * 16 + t] = uu;
            }
            __syncthreads();

            // sigma contribution (K still in registers/LDS copy)
            #pragma unroll
            for (int r = 0; r < 16; r++) acc += uu_s[r] * kk[r];
        }

        // block partial for column sums (8 KB)
        ((f4*)partial)[(size_t)q * 512 + t] = acc;
        gbar(&bar[2 * it], t);

        // distributed v-reduce: block q produces f4-slots [g*16, g*16+16) of batch b
        {
            int c4 = g * 16 + (t & 15);
            int prow = t >> 4;     // 0..31
            f4 pv = ((const f4*)partial)[(size_t)(b * 32 + prow) * 512 + c4];
            #pragma unroll
            for (int off = 16; off <= 32; off <<= 1) {
                pv.x += __shfl_xor(pv.x, off);
                pv.y += __shfl_xor(pv.y, off);
                pv.z += __shfl_xor(pv.z, off);
                pv.w += __shfl_xor(pv.w, off);
            }
            if (l < 16) sgbuf[w * 16 + l] = pv;
            __syncthreads();
            if (t < 16) {
                f4 s = sgbuf[t];
                #pragma unroll
                for (int ww = 1; ww < 8; ww++) s += sgbuf[ww * 16 + t];
                f4 vv;
                vv.x = 1.0f / (s.x + EPS_SINK);
                vv.y = 1.0f / (s.y + EPS_SINK);
                vv.z = 1.0f / (s.z + EPS_SINK);
                vv.w = 1.0f / (s.w + EPS_SINK);
                ((f4*)vglob)[q * 16 + t] = vv;
            }
        }
        gbar(&bar[2 * it + 1], t);

        // reload this thread's v slice
        vk = ((const f4*)vglob)[b * 512 + t];
    }
}

// ---------------- argmax over columns of P = (u*K)*v (R2-proven) ----------------
__global__ __launch_bounds__(256) void argmax_k(const float* __restrict__ Kd,
                                                const float* __restrict__ u,
                                                const float* __restrict__ v,
                                                int* __restrict__ out) {
    int w = (blockIdx.x * 256 + threadIdx.x) >> 6;   // wave per row
    int lane = threadIdx.x & 63;
    int b = w >> 11, i = w & 2047;
    float uu = u[(size_t)b * NN + i];
    const float4* Kr = (const float4*)(Kd + ((size_t)b * NN + i) * NN);
    const float4* v4 = (const float4*)(v + (size_t)b * NN);
    float best = -1.0f;
    int bidx = 0;
    for (int it = 0; it < 8; it++) {
        int c4 = it * 64 + lane;
        float4 kk = Kr[c4];
        float4 vv = v4[c4];
        int j = c4 * 4;
        float p0 = (uu * kk.x) * vv.x;
        float p1 = (uu * kk.y) * vv.y;
        float p2 = (uu * kk.z) * vv.z;
        float p3 = (uu * kk.w) * vv.w;
        if (p0 > best) { best = p0; bidx = j; }
        if (p1 > best) { best = p1; bidx = j + 1; }
        if (p2 > best) { best = p2; bidx = j + 2; }
        if (p3 > best) { best = p3; bidx = j + 3; }
    }
    #pragma unroll
    for (int off = 32; off; off >>= 1) {
        float ov = __shfl_xor(best, off);
        int oi = __shfl_xor(bidx, off);
        if (ov > best || (ov == best && oi < bidx)) { best = ov; bidx = oi; }
    }
    if (lane == 0) out[(size_t)b * NN + i] = bidx;
}

extern "C" void kernel_launch(void* const* d_in, const int* in_sizes, int n_in,
                              void* d_out, int out_size, void* d_ws, size_t ws_size,
                              hipStream_t stream) {
    const float* x0 = (const float*)d_in[0];
    const float* x1 = (const float*)d_in[1];
    int* out = (int*)d_out;
    char* ws = (char*)d_ws;

    // ws layout (bytes)
    float* Kd      = (float*)(ws + 0ull);                 // 134217728
    float* partial = (float*)(ws + 134217728ull);         // 2097152
    float* vglob   = (float*)(ws + 136314880ull);         // 65536
    float* uglob   = (float*)(ws + 136380416ull);         // 65536
    float* sq0     = (float*)(ws + 136445952ull);         // 65536
    float* sq1     = (float*)(ws + 136511488ull);         // 65536
    unsigned* maxd = (unsigned*)(ws + 136577024ull);      // 32
    unsigned* bar  = (unsigned*)(ws + 136577056ull);      // 512

    init_k<<<1, 256, 0, stream>>>(maxd, bar);
    sq_k<<<8192, 256, 0, stream>>>(x0, x1, sq0, sq1);
    distc_k<0><<<4096, 256, 0, stream>>>(x0, x1, sq0, sq1, Kd, maxd);
    distc_k<1><<<4096, 256, 0, stream>>>(x0, x1, sq0, sq1, Kd, maxd);
    persist_k<<<256, 512, 0, stream>>>(Kd, partial, vglob, uglob, bar);
    argmax_k<<<4096, 256, 0, stream>>>(Kd, uglob, vglob, out);
}

// Round 9
// 1751.118 us; speedup vs baseline: 3.1449x; 2.4082x over previous
//
#include <hip/hip_runtime.h>
#include <stdint.h>

#define BB 8
#define NN 2048
#define DD 64
#define REGv 0.1f
#define NUM_ITERS 50
#define EPS_NORM 1e-8f
#define EPS_SINK 1e-10f

typedef float f4 __attribute__((ext_vector_type(4)));
typedef __attribute__((address_space(1))) const void GV;
typedef __attribute__((address_space(3))) void LV;

__device__ __forceinline__ float dotf4(f4 a, f4 b) {
    return a.x * b.x + a.y * b.y + a.z * b.z + a.w * b.w;
}

// ---------------- init: maxd2 = 0, per-(iter,batch) barrier counters = 0 ----------------
__global__ void init_k(unsigned* maxd, unsigned* bar) {
    int t = blockIdx.x * 256 + threadIdx.x;
    if (t < BB) maxd[t] = 0u;
    if (t < NUM_ITERS * 8 * 32) bar[t] = 0u;   // 12800 counters (128B padded)
}

// ---------------- row squared norms (one wave per row) ----------------
__global__ void sq_k(const float* __restrict__ x0, const float* __restrict__ x1,
                     float* __restrict__ sq0, float* __restrict__ sq1) {
    int w = (blockIdx.x * 256 + threadIdx.x) >> 6;
    int lane = threadIdx.x & 63;
    if (w >= 2 * BB * NN) return;
    const float* src = (w < BB * NN) ? x0 : x1;
    int r = (w < BB * NN) ? w : w - BB * NN;
    float val = src[(size_t)r * DD + lane];
    float s = val * val;
    #pragma unroll
    for (int off = 32; off; off >>= 1) s += __shfl_xor(s, off);
    if (lane == 0) ((w < BB * NN) ? sq0 : sq1)[r] = s;
}

// ---------------- fused cdist: WRITE=0 -> max(d2); WRITE=1 -> K=exp ----------------
template<int WRITE>
__global__ __launch_bounds__(256) void distc_k(const float* __restrict__ x0,
                                               const float* __restrict__ x1,
                                               const float* __restrict__ sq0,
                                               const float* __restrict__ sq1,
                                               float* __restrict__ Kd,
                                               unsigned* __restrict__ maxd) {
    __shared__ float x0s[128 * 64];
    __shared__ float x1t[64 * 68];
    __shared__ float wred[4];
    int bid = blockIdx.x;
    int b = bid >> 9;
    int tile = bid & 511;
    int ti = tile >> 5, tj = tile & 31;
    int i0 = ti * 128, j0 = tj * 64;
    int t = threadIdx.x;

    const float4* g0 = (const float4*)(x0 + ((size_t)b * NN + i0) * DD);
    #pragma unroll
    for (int rep = 0; rep < 8; rep++) {
        int e = rep * 256 + t;
        int row = e >> 4, c4 = e & 15;
        int pc = c4 ^ ((row >> 3) & 3);     // XOR swizzle
        *(float4*)&x0s[row * 64 + pc * 4] = g0[row * 16 + c4];
    }
    const float4* g1 = (const float4*)(x1 + ((size_t)b * NN + j0) * DD);
    #pragma unroll
    for (int rep = 0; rep < 4; rep++) {
        int e = rep * 256 + t;
        int row = e >> 4, c4 = e & 15;
        float4 a = g1[row * 16 + c4];
        x1t[(c4 * 4 + 0) * 68 + row] = a.x;
        x1t[(c4 * 4 + 1) * 68 + row] = a.y;
        x1t[(c4 * 4 + 2) * 68 + row] = a.z;
        x1t[(c4 * 4 + 3) * 68 + row] = a.w;
    }
    __syncthreads();

    int tx = t & 15, ty = t >> 4;
    float4 acc4[8];
    #pragma unroll
    for (int di = 0; di < 8; di++) acc4[di] = make_float4(0.f, 0.f, 0.f, 0.f);

    #pragma unroll
    for (int k4 = 0; k4 < 16; k4++) {
        float4 b0 = *(const float4*)&x1t[(k4 * 4 + 0) * 68 + tx * 4];
        float4 b1 = *(const float4*)&x1t[(k4 * 4 + 1) * 68 + tx * 4];
        float4 b2 = *(const float4*)&x1t[(k4 * 4 + 2) * 68 + tx * 4];
        float4 b3 = *(const float4*)&x1t[(k4 * 4 + 3) * 68 + tx * 4];
        int pk = (k4 ^ (ty & 3)) << 2;
        #pragma unroll
        for (int di = 0; di < 8; di++) {
            float4 a = *(const float4*)&x0s[(ty * 8 + di) * 64 + pk];
            acc4[di].x += a.x * b0.x + a.y * b1.x + a.z * b2.x + a.w * b3.x;
            acc4[di].y += a.x * b0.y + a.y * b1.y + a.z * b2.y + a.w * b3.y;
            acc4[di].z += a.x * b0.z + a.y * b1.z + a.z * b2.z + a.w * b3.z;
            acc4[di].w += a.x * b0.w + a.y * b1.w + a.z * b2.w + a.w * b3.w;
        }
    }

    int ib = b * NN + i0 + ty * 8;
    float4 s1 = *(const float4*)&sq1[b * NN + j0 + tx * 4];

    if (WRITE) {
        float mv = sqrtf(__uint_as_float(maxd[b])) + EPS_NORM;
        #pragma unroll
        for (int di = 0; di < 8; di++) {
            float s0 = sq0[ib + di];
            float4 o;
            o.x = expf(-((sqrtf(fmaxf(s0 + s1.x - 2.f * acc4[di].x, 0.f)) / mv) / REGv));
            o.y = expf(-((sqrtf(fmaxf(s0 + s1.y - 2.f * acc4[di].y, 0.f)) / mv) / REGv));
            o.z = expf(-((sqrtf(fmaxf(s0 + s1.z - 2.f * acc4[di].z, 0.f)) / mv) / REGv));
            o.w = expf(-((sqrtf(fmaxf(s0 + s1.w - 2.f * acc4[di].w, 0.f)) / mv) / REGv));
            *(float4*)&Kd[(size_t)(ib + di) * NN + j0 + tx * 4] = o;
        }
    } else {
        float lm = 0.0f;
        #pragma unroll
        for (int di = 0; di < 8; di++) {
            float s0 = sq0[ib + di];
            lm = fmaxf(lm, fmaxf(s0 + s1.x - 2.f * acc4[di].x, 0.f));
            lm = fmaxf(lm, fmaxf(s0 + s1.y - 2.f * acc4[di].y, 0.f));
            lm = fmaxf(lm, fmaxf(s0 + s1.z - 2.f * acc4[di].z, 0.f));
            lm = fmaxf(lm, fmaxf(s0 + s1.w - 2.f * acc4[di].w, 0.f));
        }
        #pragma unroll
        for (int off = 32; off; off >>= 1) lm = fmaxf(lm, __shfl_xor(lm, off));
        if ((t & 63) == 0) wred[t >> 6] = lm;
        __syncthreads();
        if (t == 0) {
            float m = fmaxf(fmaxf(wred[0], wred[1]), fmaxf(wred[2], wred[3]));
            atomicMax(&maxd[b], __float_as_uint(m));  // d2 >= 0: uint cmp == float cmp
        }
    }
}

// ---------------- per-batch barrier (32 co-resident blocks, one-shot counter) ----------------
__device__ __forceinline__ void gbar(unsigned* c, int t, unsigned n) {
    __syncthreads();   // drains this block's stores before arrive
    if (t == 0) {
        __threadfence();                 // release (agent scope)
        atomicAdd(c, 1u);
        while (__hip_atomic_load(c, __ATOMIC_RELAXED, __HIP_MEMORY_SCOPE_AGENT) < n)
            __builtin_amdgcn_s_sleep(2);
        __threadfence();                 // acquire
    }
    __syncthreads();
}

// ---------------- persistent Sinkhorn: row-split waves + async LDS ring ----------------
// 256 blocks x 512 threads (8 waves), 1 block/CU (147 KB LDS).
// Block q: batch b=q&7 (XCD-pinned), group g=q>>3, rows g*64..g*64+63.
// Chunk c (8 rows): wave w owns row c*8+w entirely -> u is wave-local (no block sync).
// Staging: wave w DMAs its own row into its own rowslot of S[c&1] -> no cross-wave
// hazard; per-wave counted vmcnt(8) keeps the next chunk always in flight.
// sigma in sg[8] f4 regs (latin-rotated cols: slot k <-> chunk (w+k)&7) merged once/iter.
__global__ __launch_bounds__(512)
void persist_k(const float* __restrict__ Kd,
               float* __restrict__ partial,
               float* __restrict__ vglob,
               float* __restrict__ uglob,
               unsigned* __restrict__ bar) {
    __shared__ f4 S[2][8][512];     // 128 KB staging ring (2 chunks x 8 rows x 8KB)
    __shared__ f4 vbuf4[512];       // 8 KB
    __shared__ f4 sgbuf[512];       // 8 KB

    const int t = threadIdx.x;
    const int l = t & 63;
    const int w = t >> 6;
    const int q = blockIdx.x;
    const int b = q & 7;
    const int g = q >> 3;
    const size_t rowbase = (size_t)b * NN + (size_t)g * 64;

    vbuf4[t] = (f4){1.0f / NN, 1.0f / NN, 1.0f / NN, 1.0f / NN};
    __syncthreads();

#define STAGE(c_) do { \
    const float* rp_ = Kd + (rowbase + (size_t)(c_) * 8 + (size_t)w) * NN; \
    char* lb_ = (char*)(&S[(c_) & 1][w][0]); \
    _Pragma("unroll") \
    for (int j_ = 0; j_ < 8; ++j_) { \
        __builtin_amdgcn_global_load_lds((GV*)(rp_ + (j_ * 64 + l) * 4), \
                                         (LV*)(lb_ + j_ * 1024), 16, 0, 0); \
    } } while (0)

    STAGE(0); STAGE(1);

    int db = 0;
    for (int it = 0; it < NUM_ITERS; ++it) {
        const bool last = (it == NUM_ITERS - 1);
        f4 sg[8];
        #pragma unroll
        for (int k = 0; k < 8; ++k) sg[k] = (f4){0.f, 0.f, 0.f, 0.f};

        for (int c = 0; c < 8; ++c) {
            if (c < 7) asm volatile("s_waitcnt vmcnt(8)" ::: "memory");
            else       asm volatile("s_waitcnt vmcnt(0)" ::: "memory");
            __builtin_amdgcn_sched_barrier(0);

            f4 kk[8];
            #pragma unroll
            for (int k = 0; k < 8; ++k) kk[k] = S[c & 1][w][(((w + k) & 7) << 6) + l];
            float dp = 0.f;
            #pragma unroll
            for (int k = 0; k < 8; ++k) dp += dotf4(kk[k], vbuf4[(((w + k) & 7) << 6) + l]);
            #pragma unroll
            for (int off = 32; off; off >>= 1) dp += __shfl_xor(dp, off);
            float uu = 1.0f / (dp + EPS_SINK);
            if (last && l == 0) uglob[rowbase + (size_t)c * 8 + w] = uu;
            #pragma unroll
            for (int k = 0; k < 8; ++k) sg[k] += uu * kk[k];

            if (c < 6) {
                asm volatile("s_waitcnt lgkmcnt(0)" ::: "memory");   // my ds_reads done
                __builtin_amdgcn_sched_barrier(0);
                STAGE(c + 2);    // refill the buf I just finished reading (own rowslot only)
            }
        }

        // ---- sigma merge: 8 latin-square steps (disjoint regions per step) ----
        #pragma unroll
        for (int s = 0; s < 8; ++s) {
            int idx = (((w + s) & 7) << 6) + l;
            if (s == 0) sgbuf[idx] = sg[0];
            else        sgbuf[idx] += sg[s];
            __syncthreads();
        }

        // ---- block partial (8 KB, double-buffered across iters) ----
        ((f4*)partial)[(size_t)((db * 8 + b) * 32 + g) * 512 + t] = sgbuf[t];
        gbar(bar + ((size_t)it * 8 + b) * 32, t, 32u);

        // ---- vred: every block reduces all 32 partials for its own column ----
        f4 vs = (f4){0.f, 0.f, 0.f, 0.f};
        const f4* pp = (const f4*)partial + (size_t)(db * 8 + b) * 32 * 512 + t;
        #pragma unroll
        for (int gg = 0; gg < 32; ++gg) vs += pp[gg * 512];
        f4 vv;
        vv.x = 1.0f / (vs.x + EPS_SINK);
        vv.y = 1.0f / (vs.y + EPS_SINK);
        vv.z = 1.0f / (vs.z + EPS_SINK);
        vv.w = 1.0f / (vs.w + EPS_SINK);
        if (last && g == 0) ((f4*)vglob)[b * 512 + t] = vv;
        vbuf4[t] = vv;
        __syncthreads();
        db ^= 1;
        if (!last) { STAGE(0); STAGE(1); }   // prefetch next iter's first chunks
    }
#undef STAGE
}

// ---------------- argmax over columns of P = (u*K)*v (R2-proven) ----------------
__global__ __launch_bounds__(256) void argmax_k(const float* __restrict__ Kd,
                                                const float* __restrict__ u,
                                                const float* __restrict__ v,
                                                int* __restrict__ out) {
    int w = (blockIdx.x * 256 + threadIdx.x) >> 6;   // wave per row
    int lane = threadIdx.x & 63;
    int b = w >> 11, i = w & 2047;
    float uu = u[(size_t)b * NN + i];
    const float4* Kr = (const float4*)(Kd + ((size_t)b * NN + i) * NN);
    const float4* v4 = (const float4*)(v + (size_t)b * NN);
    float best = -1.0f;
    int bidx = 0;
    for (int it = 0; it < 8; it++) {
        int c4 = it * 64 + lane;
        float4 kk = Kr[c4];
        float4 vv = v4[c4];
        int j = c4 * 4;
        float p0 = (uu * kk.x) * vv.x;
        float p1 = (uu * kk.y) * vv.y;
        float p2 = (uu * kk.z) * vv.z;
        float p3 = (uu * kk.w) * vv.w;
        if (p0 > best) { best = p0; bidx = j; }
        if (p1 > best) { best = p1; bidx = j + 1; }
        if (p2 > best) { best = p2; bidx = j + 2; }
        if (p3 > best) { best = p3; bidx = j + 3; }
    }
    #pragma unroll
    for (int off = 32; off; off >>= 1) {
        float ov = __shfl_xor(best, off);
        int oi = __shfl_xor(bidx, off);
        if (ov > best || (ov == best && oi < bidx)) { best = ov; bidx = oi; }
    }
    if (lane == 0) out[(size_t)b * NN + i] = bidx;
}

extern "C" void kernel_launch(void* const* d_in, const int* in_sizes, int n_in,
                              void* d_out, int out_size, void* d_ws, size_t ws_size,
                              hipStream_t stream) {
    const float* x0 = (const float*)d_in[0];
    const float* x1 = (const float*)d_in[1];
    int* out = (int*)d_out;
    char* ws = (char*)d_ws;

    // ws layout (bytes), all 128-aligned
    float* Kd      = (float*)(ws + 0ull);                 // 134217728
    float* partial = (float*)(ws + 134217728ull);         // 4194304 (2 x 8 x 32 x 512 f4)
    float* vglob   = (float*)(ws + 138412032ull);         // 65536
    float* uglob   = (float*)(ws + 138477568ull);         // 65536
    float* sq0     = (float*)(ws + 138543104ull);         // 65536
    float* sq1     = (float*)(ws + 138608640ull);         // 65536
    unsigned* maxd = (unsigned*)(ws + 138674176ull);      // 128
    unsigned* bar  = (unsigned*)(ws + 138674304ull);      // 51200

    init_k<<<50, 256, 0, stream>>>(maxd, bar);
    sq_k<<<8192, 256, 0, stream>>>(x0, x1, sq0, sq1);
    distc_k<0><<<4096, 256, 0, stream>>>(x0, x1, sq0, sq1, Kd, maxd);
    distc_k<1><<<4096, 256, 0, stream>>>(x0, x1, sq0, sq1, Kd, maxd);
    persist_k<<<256, 512, 0, stream>>>(Kd, partial, vglob, uglob, bar);
    argmax_k<<<4096, 256, 0, stream>>>(Kd, uglob, vglob, out);
}